// Round 6
// baseline (207.647 us; speedup 1.0000x reference)
//
#include <hip/hip_runtime.h>
#include <stdint.h>

typedef __attribute__((ext_vector_type(4))) float floatx4;
typedef __attribute__((ext_vector_type(8))) __bf16 bf16x8;

#define K_DIM 2048
#define NH 96
#define M_ROWS 16384
#define BK 64
#define HALF_K 1024
#define STEPS (HALF_K / BK)            // 16 per K-half
#define WSLAB_BYTES (NH * BK * 2)      // 12288 B per packed W slab (no pad)
#define NSLAB (K_DIM / BK)             // 32
#define WPACK_BYTES (NSLAB * WSLAB_BYTES)

// LDS map (dynamic, 114688 B): xs [buf][half] 16 KB each at buf*32768+half*16384;
// ws [buf][half] 12 KB each at 65536 + buf*24576 + half*12288.
#define XS_OFF(buf, half) ((buf) * 32768 + (half) * 16384)
#define WS_OFF(buf, half) (65536 + (buf) * 24576 + (half) * 12288)
#define SMEM_BYTES 114688

// async global->LDS, 16B/lane; global addr per-lane, LDS dest = uniform base + lane*16
#define GLD16(gp, lp) __builtin_amdgcn_global_load_lds( \
    (const __attribute__((address_space(1))) uint32_t*)(gp), \
    (__attribute__((address_space(3))) uint32_t*)(lp), 16, 0, 0)

// s_waitcnt imm: vmcnt[3:0] (+[15:14]), expcnt[6:4], lgkmcnt[11:8]
#define WAIT_VM_LGKM0(n) __builtin_amdgcn_s_waitcnt((0 << 8) | (7 << 4) | (n))
#define WAIT_LGKM0()     __builtin_amdgcn_s_waitcnt((3 << 14) | (0 << 8) | (7 << 4) | 15)

#define BARRIER() do { asm volatile("" ::: "memory"); \
                       __builtin_amdgcn_s_barrier();  \
                       asm volatile("" ::: "memory"); } while (0)

// --- Kernel 1: pack W into bf16 B-frags, BK=64 slabs.
// Slab g, frag (f,t), lane l, elem j = W[t*16+(l&15)][g*64+f*32+(l>>4)*8+j]
__global__ __launch_bounds__(256) void wpack_kernel(const float* __restrict__ W,
                                                    uint8_t* __restrict__ WbF) {
    int u = blockIdx.x * 256 + threadIdx.x;   // 24576 = 32 slabs * 12 frags * 64 lanes
    int l  = u & 63;
    int fr = u >> 6;            // fr = g*12 + f*6 + t
    int t  = fr % 6;
    int f  = (fr / 6) & 1;
    int g  = fr / 12;
    int head = t * 16 + (l & 15);
    int k    = g * 64 + f * 32 + (l >> 4) * 8;
    const float* wp = W + (size_t)head * K_DIM + k;
    float4 v0 = *(const float4*)wp;
    float4 v1 = *(const float4*)(wp + 4);
    bf16x8 o;
    o[0] = (__bf16)v0.x; o[1] = (__bf16)v0.y; o[2] = (__bf16)v0.z; o[3] = (__bf16)v0.w;
    o[4] = (__bf16)v1.x; o[5] = (__bf16)v1.y; o[6] = (__bf16)v1.z; o[7] = (__bf16)v1.w;
    *(bf16x8*)(WbF + (size_t)g * WSLAB_BYTES + (f * 6 + t) * 1024 + l * 16) = o;
}

// --- Kernel 2: fused GEMM+reduce. Grid 256 (1 block/CU). Block = 8 waves:
// ww=w&3 -> 16-row group of the 64-row M-tile; h=w>>2 -> K-half (K=1024 each).
// BK=64 double-buffered LDS pipeline, vmcnt(7) fine waits, raw s_barrier.
// Epilogue: h=1 partials -> LDS, h=0 adds + bias + stores out. No workspace partials.
__global__ __launch_bounds__(512, 1) void mh_gemm_kernel(const float* __restrict__ x,
                                                         const uint8_t* __restrict__ WbF,
                                                         const float* __restrict__ bias,
                                                         float* __restrict__ out) {
    extern __shared__ __align__(16) uint8_t smem[];

    const int tid  = threadIdx.x;
    const int w    = tid >> 6;
    const int lane = tid & 63;
    const int n15  = lane & 15;
    const int quad = lane >> 4;
    const int ww   = w & 3;       // M-group
    const int h    = w >> 2;      // K-half
    const int m0   = (int)blockIdx.x * 64;

    // bias preload: 6 regs
    float bv[6];
#pragma unroll
    for (int t = 0; t < 6; ++t) bv[t] = bias[t * 16 + n15];

    // per-lane x source pointers for the 4 staging GLD16s (XOR-swizzled chunks)
    const float* xsrc[4];
    {
        const float* xg = x + (size_t)m0 * K_DIM + h * HALF_K;
        const int l4 = lane >> 4;
#pragma unroll
        for (int p = 0; p < 4; ++p) {
            int r  = ww * 16 + p * 4 + l4;          // row within tile
            int ch = n15 ^ (r & 15);                // global 16B-chunk for slot n15
            xsrc[p] = xg + (size_t)r * K_DIM + ch * 4;
        }
    }
    const uint8_t* wsrc = WbF + (size_t)(h * STEPS) * WSLAB_BYTES + (ww * 3) * 1024 + lane * 16;

    auto stage = [&](int s, int b) {
        uint8_t* xsd = smem + XS_OFF(b, h) + (ww * 16) * 256;   // 16 rows x 256B
#pragma unroll
        for (int p = 0; p < 4; ++p)
            GLD16(xsrc[p] + s * BK, xsd + p * 1024);
        const uint8_t* wg = wsrc + (size_t)s * WSLAB_BYTES;
        uint8_t* wsd = smem + WS_OFF(b, h) + (ww * 3) * 1024;
#pragma unroll
        for (int j = 0; j < 3; ++j)
            GLD16(wg + j * 1024, wsd + j * 1024);
    };

    floatx4 acc[6] = {};

    auto compute = [&](int b) {
        const float*   xsd = (const float*)(smem + XS_OFF(b, h));
        const uint8_t* wsd = smem + WS_OFF(b, h);
        const float* rowp = xsd + (ww * 16 + n15) * 64;
        bf16x8 af[2];
#pragma unroll
        for (int f = 0; f < 2; ++f) {
            int c0 = f * 8 + quad * 2;
            float4 lo = *(const float4*)(rowp + ((c0 ^ n15) << 2));
            float4 hi = *(const float4*)(rowp + (((c0 + 1) ^ n15) << 2));
            bf16x8 a;
            a[0] = (__bf16)lo.x; a[1] = (__bf16)lo.y;
            a[2] = (__bf16)lo.z; a[3] = (__bf16)lo.w;
            a[4] = (__bf16)hi.x; a[5] = (__bf16)hi.y;
            a[6] = (__bf16)hi.z; a[7] = (__bf16)hi.w;
            af[f] = a;
        }
#pragma unroll
        for (int t = 0; t < 6; ++t) {
            uint4 b0 = *(const uint4*)(wsd + (0 * 6 + t) * 1024 + lane * 16);
            uint4 b1 = *(const uint4*)(wsd + (1 * 6 + t) * 1024 + lane * 16);
            acc[t] = __builtin_amdgcn_mfma_f32_16x16x32_bf16(
                af[0], __builtin_bit_cast(bf16x8, b0), acc[t], 0, 0, 0);
            acc[t] = __builtin_amdgcn_mfma_f32_16x16x32_bf16(
                af[1], __builtin_bit_cast(bf16x8, b1), acc[t], 0, 0, 0);
        }
    };

    stage(0, 0);
    stage(1, 1);
    for (int s = 0; s < STEPS; ++s) {
        if (s < STEPS - 1) WAIT_VM_LGKM0(7);   // slab s landed; s+1's 7 stay in flight
        else               WAIT_VM_LGKM0(0);
        BARRIER();
        compute(s & 1);
        WAIT_LGKM0();                          // my LDS reads drained before buffer reuse
        BARRIER();
        if (s + 2 < STEPS) stage(s + 2, s & 1);
    }

    // --- in-block K-half reduction (reuse xs buf0 region), bias, store ---
    float* red = (float*)smem;                 // [4 groups][64 lanes][25] = 25.6 KB
    if (h == 1) {
#pragma unroll
        for (int t = 0; t < 6; ++t)
#pragma unroll
            for (int r = 0; r < 4; ++r)
                red[(ww * 64 + lane) * 25 + t * 4 + r] = acc[t][r];
    }
    WAIT_LGKM0();
    BARRIER();
    if (h == 0) {
        const float* rp = &red[(ww * 64 + lane) * 25];
        const int orow = m0 + ww * 16 + quad * 4;
#pragma unroll
        for (int t = 0; t < 6; ++t) {
            const int hcol = t * 16 + n15;
#pragma unroll
            for (int r = 0; r < 4; ++r)
                out[(size_t)(orow + r) * NH + hcol] = acc[t][r] + rp[t * 4 + r] + bv[t];
        }
    }
}

extern "C" void kernel_launch(void* const* d_in, const int* in_sizes, int n_in,
                              void* d_out, int out_size, void* d_ws, size_t ws_size,
                              hipStream_t stream) {
    const float* x = (const float*)d_in[0];
    const float* W = (const float*)d_in[1];
    const float* b = (const float*)d_in[2];
    float* out = (float*)d_out;
    uint8_t* WbF = (uint8_t*)d_ws;            // 393216 B

    static int attr_set = 0;                  // idempotent host-side attribute
    if (!attr_set) {
        hipFuncSetAttribute((const void*)mh_gemm_kernel,
                            hipFuncAttributeMaxDynamicSharedMemorySize, SMEM_BYTES);
        attr_set = 1;
    }

    wpack_kernel<<<96, 256, 0, stream>>>(W, WbF);
    mh_gemm_kernel<<<M_ROWS / 64, 512, SMEM_BYTES, stream>>>(x, WbF, b, out);
}